// Round 1
// baseline (204.850 us; speedup 1.0000x reference)
//
#include <hip/hip_runtime.h>

#define NUM_CLASSES 10
#define CELL_P 15
constexpr float LAMBDA_COORD = 5.0f;
constexpr float LAMBDA_NOOBJ = 0.5f;

// YOLO loss: per-cell (15 floats) elementwise math + global reduction to 4 scalars.
// out[0]=total, out[1]=coord, out[2]=conf, out[3]=class
__global__ __launch_bounds__(256) void yolo_loss_kernel(
    const float* __restrict__ pred,
    const float* __restrict__ tgt,
    float* __restrict__ out,
    long long ncells)
{
    long long idx    = (long long)blockIdx.x * blockDim.x + threadIdx.x;
    long long stride = (long long)gridDim.x * blockDim.x;

    float coord = 0.f, conf = 0.f, cls = 0.f;

    for (long long i = idx; i < ncells; i += stride) {
        const float* p = pred + i * CELL_P;
        const float* t = tgt  + i * CELL_P;

        float t4  = t[4];
        bool  obj = t4 > 0.f;

        // coordinate squared error (xywh)
        float csq = 0.f;
#pragma unroll
        for (int j = 0; j < 4; ++j) {
            float d = p[j] - t[j];
            csq += d * d;
        }

        // sigmoid(conf)
        float sig = 1.f / (1.f + __expf(-p[4]));

        // classification squared error
        float clsq = 0.f;
#pragma unroll
        for (int j = 5; j < 15; ++j) {
            float d = p[j] - t[j];
            clsq += d * d;
        }

        if (obj) {
            coord += csq;
            float dc = sig - t4;
            conf += dc * dc;
            cls  += clsq * (1.0f / NUM_CLASSES);
        } else {
            conf += LAMBDA_NOOBJ * sig * sig;
        }
    }

    // wave (64-lane) shuffle reduction
#pragma unroll
    for (int off = 32; off > 0; off >>= 1) {
        coord += __shfl_down(coord, off);
        conf  += __shfl_down(conf,  off);
        cls   += __shfl_down(cls,   off);
    }

    __shared__ float s[3][4];  // 256 threads = 4 waves
    int wave = threadIdx.x >> 6;
    int lane = threadIdx.x & 63;
    if (lane == 0) {
        s[0][wave] = coord;
        s[1][wave] = conf;
        s[2][wave] = cls;
    }
    __syncthreads();

    if (threadIdx.x == 0) {
        float c0 = 0.f, c1 = 0.f, c2 = 0.f;
#pragma unroll
        for (int w = 0; w < 4; ++w) {
            c0 += s[0][w];
            c1 += s[1][w];
            c2 += s[2][w];
        }
        atomicAdd(&out[1], LAMBDA_COORD * c0);
        atomicAdd(&out[2], c1);
        atomicAdd(&out[3], c2);
    }
}

__global__ void yolo_finalize_kernel(float* __restrict__ out) {
    out[0] = out[1] + out[2] + out[3];
}

extern "C" void kernel_launch(void* const* d_in, const int* in_sizes, int n_in,
                              void* d_out, int out_size, void* d_ws, size_t ws_size,
                              hipStream_t stream) {
    const float* pred = (const float*)d_in[0];
    const float* tgt  = (const float*)d_in[1];
    float* out = (float*)d_out;

    long long total_elems = (long long)in_sizes[0];     // B*S*S*15
    long long ncells      = total_elems / CELL_P;       // B*S*S

    // harness poisons d_out with 0xAA before every timed launch
    hipMemsetAsync(d_out, 0, 4 * sizeof(float), stream);

    const int block  = 256;
    const int blocks = 1024;  // grid-stride; ~5.3 cells/thread, 256 CUs x 4 blocks
    yolo_loss_kernel<<<blocks, block, 0, stream>>>(pred, tgt, out, ncells);
    yolo_finalize_kernel<<<1, 1, 0, stream>>>(out);
}

// Round 2
// 182.853 us; speedup vs baseline: 1.1203x; 1.1203x over previous
//
#include <hip/hip_runtime.h>

constexpr int   NUM_CLASSES  = 10;
constexpr float LAMBDA_COORD = 5.0f;
constexpr float LAMBDA_NOOBJ = 0.5f;
constexpr int   BLOCK = 256;
constexpr int   NBLOCKS_MAX = 2048;

// Flat-stream formulation: thread k handles float4 k of both pred and tgt
// (fully coalesced 16B loads). Element position pos=4k+m maps to
// cell=pos/15, j=pos%15; obj flag read via near-coalesced L1-hit load of
// tgt[cell*15+4]. Partials per block -> ws (SoA), no atomics.
__global__ __launch_bounds__(BLOCK) void yolo_main(
    const float4* __restrict__ pred4,
    const float4* __restrict__ tgt4,
    const float*  __restrict__ tgt,
    float* __restrict__ ws,
    unsigned n4, unsigned nblocks)
{
    unsigned idx    = blockIdx.x * BLOCK + threadIdx.x;
    unsigned stride = nblocks * BLOCK;

    float coord = 0.f, conf = 0.f, cls = 0.f;

    for (unsigned k = idx; k < n4; k += stride) {
        float4 p = pred4[k];
        float4 t = tgt4[k];
        unsigned base  = 4u * k;
        unsigned cell0 = base / 15u;            // magic-mul, cheap
        unsigned j0    = base - cell0 * 15u;

        // obj flags of the (at most 2) cells this float4 touches.
        // crossing happens iff j0 >= 12. These loads land inside the 1KB
        // region the wave just streamed -> L1 hits.
        float t4a = tgt[cell0 * 15u + 4u];
        float t4b = (j0 >= 12u) ? tgt[cell0 * 15u + 19u] : t4a;

        float pm[4] = {p.x, p.y, p.z, p.w};
        float tm[4] = {t.x, t.y, t.z, t.w};

#pragma unroll
        for (int m = 0; m < 4; ++m) {
            unsigned j      = j0 + (unsigned)m;
            bool     second = j >= 15u;
            unsigned jj     = second ? j - 15u : j;
            float    t4     = second ? t4b : t4a;
            bool     obj    = t4 > 0.f;

            float d  = pm[m] - tm[m];
            float sq = d * d;

            float sig   = 1.f / (1.f + __expf(-pm[m]));
            float dsv   = sig - tm[m];           // tm[m]==t4 when jj==4
            float confv = obj ? dsv * dsv : LAMBDA_NOOBJ * sig * sig;

            if (jj < 4u)       { if (obj) coord += sq; }
            else if (jj == 4u) { conf += confv; }
            else               { if (obj) cls += sq; }
        }
    }

    // wave64 shuffle reduce
#pragma unroll
    for (int off = 32; off > 0; off >>= 1) {
        coord += __shfl_down(coord, off);
        conf  += __shfl_down(conf,  off);
        cls   += __shfl_down(cls,   off);
    }

    __shared__ float s[3][4];
    int wave = threadIdx.x >> 6, lane = threadIdx.x & 63;
    if (lane == 0) { s[0][wave] = coord; s[1][wave] = conf; s[2][wave] = cls; }
    __syncthreads();

    if (threadIdx.x == 0) {
        float c0 = s[0][0] + s[0][1] + s[0][2] + s[0][3];
        float c1 = s[1][0] + s[1][1] + s[1][2] + s[1][3];
        float c2 = s[2][0] + s[2][1] + s[2][2] + s[2][3];
        ws[blockIdx.x]               = c0;
        ws[nblocks + blockIdx.x]     = c1;
        ws[2 * nblocks + blockIdx.x] = c2;
    }
}

__global__ __launch_bounds__(BLOCK) void yolo_finalize(
    const float* __restrict__ ws, float* __restrict__ out, unsigned nblocks)
{
    float c0 = 0.f, c1 = 0.f, c2 = 0.f;
    for (unsigned i = threadIdx.x; i < nblocks; i += BLOCK) {
        c0 += ws[i];
        c1 += ws[nblocks + i];
        c2 += ws[2 * nblocks + i];
    }
#pragma unroll
    for (int off = 32; off > 0; off >>= 1) {
        c0 += __shfl_down(c0, off);
        c1 += __shfl_down(c1, off);
        c2 += __shfl_down(c2, off);
    }
    __shared__ float s[3][4];
    int wave = threadIdx.x >> 6, lane = threadIdx.x & 63;
    if (lane == 0) { s[0][wave] = c0; s[1][wave] = c1; s[2][wave] = c2; }
    __syncthreads();
    if (threadIdx.x == 0) {
        float coord = LAMBDA_COORD * (s[0][0] + s[0][1] + s[0][2] + s[0][3]);
        float conf  =                 s[1][0] + s[1][1] + s[1][2] + s[1][3];
        float cls   = (1.f / NUM_CLASSES) * (s[2][0] + s[2][1] + s[2][2] + s[2][3]);
        out[0] = coord + conf + cls;
        out[1] = coord;
        out[2] = conf;
        out[3] = cls;
    }
}

extern "C" void kernel_launch(void* const* d_in, const int* in_sizes, int n_in,
                              void* d_out, int out_size, void* d_ws, size_t ws_size,
                              hipStream_t stream) {
    const float* pred = (const float*)d_in[0];
    const float* tgt  = (const float*)d_in[1];
    float* out = (float*)d_out;
    float* ws  = (float*)d_ws;

    unsigned total = (unsigned)in_sizes[0];   // B*S*S*15 = 20,766,720 (divisible by 4)
    unsigned n4    = total / 4u;

    unsigned nblocks = NBLOCKS_MAX;
    size_t need = (size_t)nblocks * 3 * sizeof(float);
    if (need > ws_size) nblocks = (unsigned)(ws_size / (3 * sizeof(float)));

    yolo_main<<<nblocks, BLOCK, 0, stream>>>(
        (const float4*)pred, (const float4*)tgt, tgt, ws, n4, nblocks);
    yolo_finalize<<<1, BLOCK, 0, stream>>>(ws, out, nblocks);
}